// Round 10
// baseline (617.195 us; speedup 1.0000x reference)
//
#include <hip/hip_runtime.h>

// FireLSTM: x[8192,512,4] fp32 -> LSTM(H=64) -> FC(64->1), out[8192] fp32.
//
// R10: ZERO-BARRIER single-wave blocks. 1024 blocks x 64 thr = 1 wave/SIMD,
// full machine. Each wave owns 8 batches and computes ALL 16 gate tiles
// (4 types x 4 h-col groups) itself: 48x mfma_f32_16x16x32_f16 per step
// (M=16 tiles, rows 8..15 dead -> waste lands on the ~24%-utilized MFMA pipe).
// h exchange is INTRA-WAVE: ds_write -> s_waitcnt lgkmcnt(0) -> ds_read is
// ordered within one wave; there is NO s_barrier in the 512-step loop and no
// cross-SIMD coupling (R9 showed the 4-wave block barrier = ~600 cyc/step of
// coupled idle that neither pipelining nor phase offsets could remove).
// Valid cells live only in lanes g16<2; R5's proven __shfl_xor(..,32)
// redistribution gives every lane 8 cells -> 56 trans insts/wave/step.
// Kept: 7-trans cell update (merged rcp), k-slot bias (k=68,69 vs A=1.0),
// zero-C operand, fp16 XOR-swizzled double-buffered h, x staged per 32 steps
// as fp16x4 (loads float freely; no vmcnt drain -- no barriers to drain them).

typedef float f32x4 __attribute__((ext_vector_type(4)));
typedef _Float16 f16x8 __attribute__((ext_vector_type(8)));
typedef _Float16 f16x4 __attribute__((ext_vector_type(4)));

#define TSEQ 512
#define IDIM 4
#define BPW 8               // batches per wave (= per block)
#define TCH 32              // x staging chunk, in steps
#define NCH (TSEQ / TCH)
#define L2E 1.44269504088896340736f

#if __has_builtin(__builtin_amdgcn_exp2f)
#define EX2(v) __builtin_amdgcn_exp2f(v)
#else
#define EX2(v) exp2f(v)
#endif
#define RCP(v) __builtin_amdgcn_rcpf(v)

__global__ __launch_bounds__(64, 1) void lstm_fused(
    const float* __restrict__ x,
    const float* __restrict__ W_ih,
    const float* __restrict__ W_hh,
    const float* __restrict__ b_ih,
    const float* __restrict__ b_hh,
    const float* __restrict__ W_fc,
    const float* __restrict__ b_fc,
    float* __restrict__ out)
{
    __shared__ __align__(16) _Float16 hbuf[2][16 * 64];   // 4 KB; rows 8-15 stay 0
    __shared__ __align__(16) f16x4    xstage[2][16][33];  // 8448 B; rows 8-15 stay 0

    const int lane = threadIdx.x;    // 0..63 (one wave per block)
    const int b0   = blockIdx.x * BPW;
    const int r    = lane & 15;      // D col (gate within tile) / A row (batch)
    const int g16  = lane >> 4;      // k-group

    // ---- B-fragments: ALL 16 tiles (type t4 x col-group cg), K=96, scaled ----
    // k = ks*32 + 8*g16 + j. ks=2: k=64..67 -> W_ih, 68,69 -> bias hi/lo
    // (vs A=1.0), k>=70 -> 0.  192 VGPR; 1 wave/SIMD so budget is 512.
    f16x8 bfrag[4][4][3];
    #pragma unroll
    for (int t4 = 0; t4 < 4; ++t4) {
        const float sc = (t4 == 2) ? 2.0f * L2E : L2E;   // g-gate gets tanh's 2x
        #pragma unroll
        for (int cg = 0; cg < 4; ++cg) {
            const int g = t4 * 64 + cg * 16 + r;         // gate row
            #pragma unroll
            for (int ks = 0; ks < 2; ++ks) {             // k 0..63: W_hh
                const float* p = W_hh + g * 64 + ks * 32 + g16 * 8;
                f16x8 f;
                #pragma unroll
                for (int j = 0; j < 8; ++j) f[j] = (_Float16)(p[j] * sc);
                bfrag[t4][cg][ks] = f;
            }
            f16x8 f;
            #pragma unroll
            for (int j = 0; j < 8; ++j) f[j] = (_Float16)0.0f;
            if (g16 == 0) {
                #pragma unroll
                for (int j = 0; j < 4; ++j) f[j] = (_Float16)(W_ih[g * IDIM + j] * sc);
                float biasf = (b_ih[g] + b_hh[g]) * sc;
                _Float16 hi = (_Float16)biasf;
                f[4] = hi;
                f[5] = (_Float16)(biasf - (float)hi);
            }
            bfrag[t4][cg][2] = f;
        }
    }
    const float wfc = W_fc[lane];
    const float bfc = b_fc[0];
    const f32x4 zero4 = {0.f, 0.f, 0.f, 0.f};

    // cell state: lane owns cells (bat0+q, h=cg*16+r), q=0,1
    float c_reg[4][2];
    #pragma unroll
    for (int cg = 0; cg < 4; ++cg) { c_reg[cg][0] = 0.f; c_reg[cg][1] = 0.f; }

    // zero hbuf (both parities; rows 8-15 stay 0 forever) and xstage
    for (int i = lane; i < 2 * 16 * 64; i += 64)
        ((_Float16*)&hbuf[0][0])[i] = (_Float16)0.0f;
    {
        f16x4 z; z[0] = z[1] = z[2] = z[3] = (_Float16)0.0f;
        for (int i = lane; i < 2 * 16 * 33; i += 64) (&xstage[0][0][0])[i] = z;
    }

    // ---- x: thread loads row (lane>>3), steps (lane&7)*4 + 0..3 per chunk ----
    const int xr = lane >> 3;            // 0..7
    const int sq = (lane & 7) * 4;       // 4 consecutive steps within chunk
    const float* xg = x + ((size_t)(b0 + xr) * TSEQ + sq) * IDIM;
    float4 xp[4];
    #pragma unroll
    for (int j = 0; j < 4; ++j) xp[j] = *(const float4*)(xg + j * IDIM);
    // stage chunk 0 into xbuf 0
    #pragma unroll
    for (int j = 0; j < 4; ++j) {
        f16x4 s;
        s[0] = (_Float16)xp[j].x; s[1] = (_Float16)xp[j].y;
        s[2] = (_Float16)xp[j].z; s[3] = (_Float16)xp[j].w;
        xstage[0][xr][sq + j] = s;
    }
    asm volatile("s_waitcnt lgkmcnt(0)" ::: "memory");   // intra-wave visibility
    #pragma unroll
    for (int j = 0; j < 4; ++j) xp[j] = *(const float4*)(xg + (TCH + j) * IDIM);

    // ---- precomputed LDS byte offsets ----
    const int hbase = r * 128;
    const int hs0 = ((g16 + 0) << 4) ^ ((r & 7) << 4);
    const int hs1 = ((g16 + 4) << 4) ^ ((r & 7) << 4);
    // cell ownership after shfl_xor(32): g16=0->bat{0,1}, 1->{4,5}, 2->{2,3}, 3->{6,7}
    const int bat0 = ((g16 & 1) << 2) | ((g16 >> 1) << 1);
    int hw[4][2];
    #pragma unroll
    for (int cg = 0; cg < 4; ++cg)
        #pragma unroll
        for (int q = 0; q < 2; ++q) {
            const int bat = bat0 + q;
            hw[cg][q] = (bat * 128 + (cg * 16 + r) * 2) ^ ((bat & 7) << 4);
        }
    const bool low = (lane < 32);
    char* hbB = (char*)&hbuf[0][0];
    const char* xsB = (const char*)&xstage[0][0][0];

    auto step = [&](int t, int P) {
        const char* rb = hbB + P * 2048;          // h_{t-1}
        char*       wb = hbB + (P ^ 1) * 2048;    // h_t
        f16x8 a0 = *(const f16x8*)(rb + hbase + hs0);
        f16x8 a1 = *(const f16x8*)(rb + hbase + hs1);
        f16x4 xv = *(const f16x4*)(xsB + ((t >> 5) & 1) * 4224 + r * 264 + (t & 31) * 8);
        f16x8 ax;
        ax[0] = xv[0]; ax[1] = xv[1]; ax[2] = xv[2]; ax[3] = xv[3];
        ax[4] = (_Float16)1.0f; ax[5] = (_Float16)1.0f;   // bias slots (k=68,69)
        ax[6] = (_Float16)0.0f; ax[7] = (_Float16)0.0f;

        #pragma unroll
        for (int cg = 0; cg < 4; ++cg) {
            f32x4 acc[4];
            #pragma unroll
            for (int t4 = 0; t4 < 4; ++t4) {
                f32x4 a;
                a = __builtin_amdgcn_mfma_f32_16x16x32_f16(a0, bfrag[t4][cg][0], zero4, 0, 0, 0);
                a = __builtin_amdgcn_mfma_f32_16x16x32_f16(a1, bfrag[t4][cg][1], a, 0, 0, 0);
                a = __builtin_amdgcn_mfma_f32_16x16x32_f16(ax, bfrag[t4][cg][2], a, 0, 0, 0);
                acc[t4] = a;
            }
            // redistribute: lower lanes keep q=0,1; upper take partner's q=2,3
            float w[4][2];
            #pragma unroll
            for (int t4 = 0; t4 < 4; ++t4) {
                float u2 = __shfl_xor(acc[t4][2], 32);
                float u3 = __shfl_xor(acc[t4][3], 32);
                w[t4][0] = low ? acc[t4][0] : u2;
                w[t4][1] = low ? acc[t4][1] : u3;
            }
            // 7-trans cell update x 2 cells
            #pragma unroll
            for (int q = 0; q < 2; ++q) {
                float ei = EX2(-w[0][q]);
                float ef = EX2(-w[1][q]);
                float eg = EX2(-w[2][q]);
                float eo = EX2(-w[3][q]);
                float A  = 1.f + ei, F = 1.f + ef;
                float Gp = 1.f + eg, Gm = 1.f - eg;
                float P2  = A * Gp;
                float num = c_reg[cg][q] * P2 + Gm * F;
                float c   = num * RCP(P2 * F);
                c_reg[cg][q] = c;
                float uc = fminf(fmaxf(c * (2.0f * L2E), -60.f), 60.f);
                float et = EX2(-uc);
                float h  = (1.f - et) * RCP((1.f + eo) * (1.f + et));
                *(_Float16*)(wb + hw[cg][q]) = (_Float16)h;
            }
        }
        // intra-wave ordering: h writes (and any x staging) complete before
        // next step's ds_reads. No s_barrier -- single wave.
        asm volatile("s_waitcnt lgkmcnt(0)" ::: "memory");
    };

    for (int t = 0; t < TSEQ; t += 2) {
        if ((t & (TCH - 1)) == 16) {
            const int c = t >> 5;                 // current chunk
            if (c + 1 < NCH) {                    // stage chunk c+1
                #pragma unroll
                for (int j = 0; j < 4; ++j) {
                    f16x4 s;
                    s[0] = (_Float16)xp[j].x; s[1] = (_Float16)xp[j].y;
                    s[2] = (_Float16)xp[j].z; s[3] = (_Float16)xp[j].w;
                    xstage[(c + 1) & 1][xr][sq + j] = s;
                }
                if (c + 2 < NCH) {                // issue loads for chunk c+2
                    #pragma unroll
                    for (int j = 0; j < 4; ++j)
                        xp[j] = *(const float4*)(xg + ((size_t)(c + 2) * TCH + j) * IDIM);
                }
            }
        }
        step(t,     0);
        step(t + 1, 1);
    }

    // ---- FC epilogue: final h in parity 0; 8 batches, reduce over 64 lanes ----
    #pragma unroll
    for (int j = 0; j < BPW; ++j) {
        const int byte = (j * 128 + lane * 2) ^ ((j & 7) << 4);
        float hv = (float)*(const _Float16*)(hbB + byte);
        float partial = hv * wfc;
        #pragma unroll
        for (int off = 32; off > 0; off >>= 1)
            partial += __shfl_down(partial, off);
        if (lane == 0) out[b0 + j] = partial + bfc;
    }
}

extern "C" void kernel_launch(void* const* d_in, const int* in_sizes, int n_in,
                              void* d_out, int out_size, void* d_ws, size_t ws_size,
                              hipStream_t stream) {
    const float* x    = (const float*)d_in[0];
    const float* W_ih = (const float*)d_in[1];
    const float* W_hh = (const float*)d_in[2];
    const float* b_ih = (const float*)d_in[3];
    const float* b_hh = (const float*)d_in[4];
    const float* W_fc = (const float*)d_in[5];
    const float* b_fc = (const float*)d_in[6];
    float* out = (float*)d_out;

    const int B = in_sizes[0] / (TSEQ * IDIM);   // 8192
    lstm_fused<<<B / BPW, 64, 0, stream>>>(x, W_ih, W_hh, b_ih, b_hh, W_fc, b_fc, out);
}

// Round 11
// 337.451 us; speedup vs baseline: 1.8290x; 1.8290x over previous
//
#include <hip/hip_runtime.h>

// FireLSTM: x[8192,512,4] fp32 -> LSTM(H=64) -> FC(64->1), out[8192] fp32.
//
// Geometry (settled by R4-R10 sweep): 512 blocks x 256 thr (4 waves) =
// 2 blocks/CU, 2 waves/SIMD (one wave of each co-resident block per SIMD --
// independent blocks, so the two waves free-run anti-phase). Block owns 16
// batches; wave wv owns h-cols [16wv,16wv+16) for all 4 gate types. Per step:
// 12x mfma_f32_16x16x32_f16 (4 tiles x K=96=[h|x+bias|pad], 3-chain); all 4
// gate types of a cell land in the same thread regs -> activation + c/h
// update fully register-local. h double-buffered fp16 XOR-swizzled LDS, ONE
// raw barrier/step (lgkmcnt-only drain; x prefetch never drained).
//
// R11 deltas vs R9 (all in-place):
//  1. setprio(1) now covers the post-barrier latency HEAD (ds_read h + ax +
//     MFMA chain), not just the MFMAs: our head outranks the partner wave's
//     trans storm; our trans at prio 0 yields to the partner's head (attn-
//     style independent-wave setprio regime, m191).
//  2. Single-sided clamp: et=exp2(-uc) can only NaN via uc<<0 (et=inf ->
//     (1-inf)*rcp(inf)=NaN); positive uc underflows et->0 harmlessly.
//     fminf dropped -> -4 VALU/step/thread.
//  3. Chunk staging de-burst: the 8-cvt+2-write+2-load burst every 32 steps
//     becomes three small events (t%32==8: stage row bb0; ==16: stage row
//     bb0+8; ==24: issue next chunk's 2 global loads) -> less per-step jitter
//     for the 4-wave rendezvous to amplify. s_sleep removed (R9: no effect).
//  Kept: 7-trans cell update (merged rcp), k-slot bias (68,69 vs A=1.0),
//  zero-C operand, double-buffered fp16x4 x staging.

typedef float f32x4 __attribute__((ext_vector_type(4)));
typedef _Float16 f16x8 __attribute__((ext_vector_type(8)));
typedef _Float16 f16x4 __attribute__((ext_vector_type(4)));

#define TSEQ 512
#define IDIM 4
#define BPB 16
#define TCH 32
#define NCH (TSEQ / TCH)
#define L2E 1.44269504088896340736f

#if __has_builtin(__builtin_amdgcn_exp2f)
#define EX2(v) __builtin_amdgcn_exp2f(v)
#else
#define EX2(v) exp2f(v)
#endif
#define RCP(v) __builtin_amdgcn_rcpf(v)

// lgkmcnt(0) makes our ds_writes visible; s_barrier rendezvous. No vmcnt
// drain (x prefetch floats free); no sched_barrier (m141: order-pinning).
#define STEP_BARRIER() do {                                   \
    asm volatile("s_waitcnt lgkmcnt(0)" ::: "memory");        \
    __builtin_amdgcn_s_barrier();                             \
} while (0)

__global__ __launch_bounds__(256, 2) void lstm_fused(
    const float* __restrict__ x,
    const float* __restrict__ W_ih,
    const float* __restrict__ W_hh,
    const float* __restrict__ b_ih,
    const float* __restrict__ b_hh,
    const float* __restrict__ W_fc,
    const float* __restrict__ b_fc,
    float* __restrict__ out)
{
    __shared__ __align__(16) _Float16 hbuf[2][BPB * 64];   // 4 KB, XOR-swizzled
    __shared__ __align__(16) f16x4    xstage[2][BPB][33];  // 2 x 4224 B

    const int tid  = threadIdx.x;
    const int lane = tid & 63;
    const int wv   = tid >> 6;
    const int b0   = blockIdx.x * BPB;
    const int r    = lane & 15;
    const int g16  = lane >> 4;

    // ---- B-fragments: 4 types x K=96, pre-scaled. k = ks*32 + 8*g16 + j.
    // ks=2: k=64..67 -> W_ih, k=68,69 -> bias hi/lo (vs A=1.0), k>=70 -> 0.
    f16x8 bfrag[4][3];
    #pragma unroll
    for (int t4 = 0; t4 < 4; ++t4) {
        const float sc = (t4 == 2) ? 2.0f * L2E : L2E;
        const int g = t4 * 64 + wv * 16 + r;
        #pragma unroll
        for (int ks = 0; ks < 2; ++ks) {
            const float* p = W_hh + g * 64 + ks * 32 + g16 * 8;
            f16x8 f;
            #pragma unroll
            for (int j = 0; j < 8; ++j) f[j] = (_Float16)(p[j] * sc);
            bfrag[t4][ks] = f;
        }
        f16x8 f;
        #pragma unroll
        for (int j = 0; j < 8; ++j) f[j] = (_Float16)0.0f;
        if (g16 == 0) {
            #pragma unroll
            for (int j = 0; j < 4; ++j) f[j] = (_Float16)(W_ih[g * IDIM + j] * sc);
            float biasf = (b_ih[g] + b_hh[g]) * sc;
            _Float16 hi = (_Float16)biasf;
            f[4] = hi;
            f[5] = (_Float16)(biasf - (float)hi);
        }
        bfrag[t4][2] = f;
    }
    const float wfc = W_fc[lane];
    const float bfc = b_fc[0];
    const f32x4 zero4 = {0.f, 0.f, 0.f, 0.f};

    float c_reg[4] = {0.f, 0.f, 0.f, 0.f};
    for (int i = tid; i < BPB * 64; i += 256) hbuf[0][i] = (_Float16)0.0f;

    // ---- x: thread loads rows bb0, bb0+8 at chunk-step tf (2 float4) ----
    const int bb0 = tid >> 5, tf = tid & 31;
    const float* xg0 = x + ((size_t)(b0 + bb0)     * TSEQ + tf) * IDIM;
    const float* xg1 = x + ((size_t)(b0 + bb0 + 8) * TSEQ + tf) * IDIM;
    float4 xn0 = *(const float4*)xg0;
    float4 xn1 = *(const float4*)xg1;
    // stage chunk 0 into xbuf 0
    {
        f16x4 s0, s1;
        s0[0] = (_Float16)xn0.x; s0[1] = (_Float16)xn0.y;
        s0[2] = (_Float16)xn0.z; s0[3] = (_Float16)xn0.w;
        s1[0] = (_Float16)xn1.x; s1[1] = (_Float16)xn1.y;
        s1[2] = (_Float16)xn1.z; s1[3] = (_Float16)xn1.w;
        xstage[0][bb0][tf]     = s0;
        xstage[0][bb0 + 8][tf] = s1;
    }
    __syncthreads();                       // once; chunk-1 loads issued after
    xn0 = *(const float4*)(xg0 + TCH * IDIM);
    xn1 = *(const float4*)(xg1 + TCH * IDIM);

    // ---- precomputed LDS byte offsets ----
    const int hbase = r * 128;
    const int hs0 = ((g16 + 0) << 4) ^ ((r & 7) << 4);
    const int hs1 = ((g16 + 4) << 4) ^ ((r & 7) << 4);
    int hw[4];
    #pragma unroll
    for (int q = 0; q < 4; ++q) {
        const int bat = 4 * g16 + q;
        hw[q] = (bat * 128 + (wv * 16 + r) * 2) ^ ((bat & 7) << 4);
    }
    char* hbB = (char*)&hbuf[0][0];
    const char* xsB = (const char*)&xstage[0][0][0];
    const int xrow = r * 33 * 8;           // row-r byte offset within one xbuf

    // one sub-step; P = parity of t (compile-time)
    auto substep = [&](int t, int P) {
        const char* rb = hbB + P * 2048;         // h_{t-1}
        char*       wb = hbB + (P ^ 1) * 2048;   // h_t
        // latency head at raised priority: reads + MFMA chain outrank the
        // partner wave's trans storm; our trans below yields at prio 0.
        __builtin_amdgcn_s_setprio(1);
        f16x8 a0 = *(const f16x8*)(rb + hbase + hs0);
        f16x8 a1 = *(const f16x8*)(rb + hbase + hs1);
        f16x4 xv = *(const f16x4*)(xsB + ((t >> 5) & 1) * 4224 + xrow + (t & 31) * 8);
        f16x8 ax;
        ax[0] = xv[0]; ax[1] = xv[1]; ax[2] = xv[2]; ax[3] = xv[3];
        ax[4] = (_Float16)1.0f; ax[5] = (_Float16)1.0f;   // bias slots (k=68,69)
        ax[6] = (_Float16)0.0f; ax[7] = (_Float16)0.0f;

        f32x4 acc[4];
        #pragma unroll
        for (int t4 = 0; t4 < 4; ++t4) {
            f32x4 a;
            a = __builtin_amdgcn_mfma_f32_16x16x32_f16(a0, bfrag[t4][0], zero4, 0, 0, 0);
            a = __builtin_amdgcn_mfma_f32_16x16x32_f16(a1, bfrag[t4][1], a, 0, 0, 0);
            a = __builtin_amdgcn_mfma_f32_16x16x32_f16(ax, bfrag[t4][2], a, 0, 0, 0);
            acc[t4] = a;
        }
        __builtin_amdgcn_s_setprio(0);

        // 7-trans cell update (4 gate exp2 + merged-rcp c + tanh exp2 + rcp)
        #pragma unroll
        for (int q = 0; q < 4; ++q) {
            float ei = EX2(-acc[0][q]);
            float ef = EX2(-acc[1][q]);
            float eg = EX2(-acc[2][q]);
            float eo = EX2(-acc[3][q]);
            float A  = 1.f + ei, F = 1.f + ef;
            float Gp = 1.f + eg, Gm = 1.f - eg;
            float P2  = A * Gp;
            float num = c_reg[q] * P2 + Gm * F;
            float c   = num * RCP(P2 * F);
            c_reg[q] = c;
            // single-sided clamp: only uc << 0 can NaN (et=inf); uc >> 0
            // just underflows et -> 0, h = rcp(1+eo): exact.
            float uc = fmaxf(c * (2.0f * L2E), -60.f);
            float et = EX2(-uc);
            float h  = (1.f - et) * RCP((1.f + eo) * (1.f + et));
            *(_Float16*)(wb + hw[q]) = (_Float16)h;
        }
        STEP_BARRIER();
    };

    for (int t = 0; t < TSEQ; t += 2) {
        const int c = t >> 5;                    // current chunk
        const int ph = t & (TCH - 1);
        if (ph == 8 && c + 1 < NCH) {            // stage row bb0 of chunk c+1
            f16x4 s0;
            s0[0] = (_Float16)xn0.x; s0[1] = (_Float16)xn0.y;
            s0[2] = (_Float16)xn0.z; s0[3] = (_Float16)xn0.w;
            (&xstage[(c + 1) & 1][0][0])[bb0 * 33 + tf] = s0;
        }
        if (ph == 16 && c + 1 < NCH) {           // stage row bb0+8 of chunk c+1
            f16x4 s1;
            s1[0] = (_Float16)xn1.x; s1[1] = (_Float16)xn1.y;
            s1[2] = (_Float16)xn1.z; s1[3] = (_Float16)xn1.w;
            (&xstage[(c + 1) & 1][0][0])[(bb0 + 8) * 33 + tf] = s1;
        }
        if (ph == 24 && c + 2 < NCH) {           // issue loads for chunk c+2
            xn0 = *(const float4*)(xg0 + (size_t)(c + 2) * TCH * IDIM);
            xn1 = *(const float4*)(xg1 + (size_t)(c + 2) * TCH * IDIM);
        }
        substep(t,     0);
        substep(t + 1, 1);
    }

    // ---- FC epilogue: final h in parity 0 (TRANS_511 wrote parity 0) ----
    #pragma unroll
    for (int q = 0; q < 4; ++q) {
        const int bat  = wv * 4 + q;
        const int byte = (bat * 128 + lane * 2) ^ ((bat & 7) << 4);
        float hv = (float)*(const _Float16*)(hbB + byte);
        float partial = hv * wfc;
        #pragma unroll
        for (int off = 32; off > 0; off >>= 1)
            partial += __shfl_down(partial, off);
        if (lane == 0) out[b0 + bat] = partial + bfc;
    }
}

extern "C" void kernel_launch(void* const* d_in, const int* in_sizes, int n_in,
                              void* d_out, int out_size, void* d_ws, size_t ws_size,
                              hipStream_t stream) {
    const float* x    = (const float*)d_in[0];
    const float* W_ih = (const float*)d_in[1];
    const float* W_hh = (const float*)d_in[2];
    const float* b_ih = (const float*)d_in[3];
    const float* b_hh = (const float*)d_in[4];
    const float* W_fc = (const float*)d_in[5];
    const float* b_fc = (const float*)d_in[6];
    float* out = (float*)d_out;

    const int B = in_sizes[0] / (TSEQ * IDIM);   // 8192
    lstm_fused<<<B / BPB, 256, 0, stream>>>(x, W_ih, W_hh, b_ih, b_hh, W_fc, b_fc, out);
}

// Round 12
// 311.544 us; speedup vs baseline: 1.9811x; 1.0832x over previous
//
#include <hip/hip_runtime.h>

// FireLSTM: x[8192,512,4] fp32 -> LSTM(H=64) -> FC(64->1), out[8192] fp32.
//
// Geometry (settled by R4-R11 sweep): 512 blocks x 256 thr (4 waves) =
// 2 blocks/CU, 2 waves/SIMD (partner wave is from an INDEPENDENT block --
// uncorrelated overlap, measured ~60% VALU busy = 1-(1-d)^2 for d~0.32).
// Block owns 16 batches; wave wv owns h-cols [16wv,16wv+16) for all 4 gate
// types. Per step: 12x mfma_f32_16x16x32_f16 (4 tiles x K=96=[h|x+bias|pad],
// 3-chain); all 4 gate types of a cell land in the same thread regs ->
// activation + c/h update fully register-local. h double-buffered fp16
// XOR-swizzled LDS, ONE raw barrier/step (lgkmcnt-only; vmcnt never drained).
//
// R12 deltas vs R9 (R11's regressors reverted):
//  1. Packed-f32 cell algebra: cells processed in PAIRS via f32x2 ext-vectors
//     -> v_pk_add/mul/fma for the ~13 non-trans ops per cell (~26 fewer VALU
//     insts/wave/step). Trans (exp2/rcp) stay scalar (no packed trans unit).
//  2. x-slice prefetch ACROSS the barrier: xv (from xstage) has no dependence
//     on the step barrier -- next step's slice is loaded before the barrier,
//     its LDS latency hides under the trans phase, and the post-barrier head
//     loses one ds_read + wait.
//  3. Single-sided clamp kept from R11 (only uc << 0 can NaN; uc >> 0
//     underflows et -> 0 harmlessly). setprio back to MFMA-only (R9 form);
//     R9's ph==16 burst staging restored (R11's de-burst added per-iter
//     branches); s_sleep kept (harmless, was in R9's 324us measurement).
//  Kept: 7-trans cell update (merged rcp), k-slot bias (68,69 vs A=1.0),
//  zero-C operand, double-buffered fp16x4 x staging.

typedef float f32x4 __attribute__((ext_vector_type(4)));
typedef float f32x2 __attribute__((ext_vector_type(2)));
typedef _Float16 f16x8 __attribute__((ext_vector_type(8)));
typedef _Float16 f16x4 __attribute__((ext_vector_type(4)));

#define TSEQ 512
#define IDIM 4
#define BPB 16
#define TCH 32
#define NCH (TSEQ / TCH)
#define L2E 1.44269504088896340736f

#if __has_builtin(__builtin_amdgcn_exp2f)
#define EX2(v) __builtin_amdgcn_exp2f(v)
#else
#define EX2(v) exp2f(v)
#endif
#define RCP(v) __builtin_amdgcn_rcpf(v)

// lgkmcnt(0) makes our ds_writes visible; s_barrier rendezvous. No vmcnt
// drain (x prefetch floats free); no sched_barrier (m141: order-pinning).
#define STEP_BARRIER() do {                                   \
    asm volatile("s_waitcnt lgkmcnt(0)" ::: "memory");        \
    __builtin_amdgcn_s_barrier();                             \
} while (0)

__global__ __launch_bounds__(256, 2) void lstm_fused(
    const float* __restrict__ x,
    const float* __restrict__ W_ih,
    const float* __restrict__ W_hh,
    const float* __restrict__ b_ih,
    const float* __restrict__ b_hh,
    const float* __restrict__ W_fc,
    const float* __restrict__ b_fc,
    float* __restrict__ out)
{
    __shared__ __align__(16) _Float16 hbuf[2][BPB * 64];   // 4 KB, XOR-swizzled
    __shared__ __align__(16) f16x4    xstage[2][BPB][33];  // 2 x 4224 B

    const int tid  = threadIdx.x;
    const int lane = tid & 63;
    const int wv   = tid >> 6;
    const int b0   = blockIdx.x * BPB;
    const int r    = lane & 15;
    const int g16  = lane >> 4;

    // ---- B-fragments: 4 types x K=96, pre-scaled. k = ks*32 + 8*g16 + j.
    // ks=2: k=64..67 -> W_ih, k=68,69 -> bias hi/lo (vs A=1.0), k>=70 -> 0.
    f16x8 bfrag[4][3];
    #pragma unroll
    for (int t4 = 0; t4 < 4; ++t4) {
        const float sc = (t4 == 2) ? 2.0f * L2E : L2E;
        const int g = t4 * 64 + wv * 16 + r;
        #pragma unroll
        for (int ks = 0; ks < 2; ++ks) {
            const float* p = W_hh + g * 64 + ks * 32 + g16 * 8;
            f16x8 f;
            #pragma unroll
            for (int j = 0; j < 8; ++j) f[j] = (_Float16)(p[j] * sc);
            bfrag[t4][ks] = f;
        }
        f16x8 f;
        #pragma unroll
        for (int j = 0; j < 8; ++j) f[j] = (_Float16)0.0f;
        if (g16 == 0) {
            #pragma unroll
            for (int j = 0; j < 4; ++j) f[j] = (_Float16)(W_ih[g * IDIM + j] * sc);
            float biasf = (b_ih[g] + b_hh[g]) * sc;
            _Float16 hi = (_Float16)biasf;
            f[4] = hi;
            f[5] = (_Float16)(biasf - (float)hi);
        }
        bfrag[t4][2] = f;
    }
    const float wfc = W_fc[lane];
    const float bfc = b_fc[0];
    const f32x4 zero4 = {0.f, 0.f, 0.f, 0.f};

    float c_reg[4] = {0.f, 0.f, 0.f, 0.f};
    for (int i = tid; i < BPB * 64; i += 256) hbuf[0][i] = (_Float16)0.0f;

    // ---- x: thread loads rows bb0, bb0+8 at chunk-step tf (2 float4) ----
    const int bb0 = tid >> 5, tf = tid & 31;
    const float* xg0 = x + ((size_t)(b0 + bb0)     * TSEQ + tf) * IDIM;
    const float* xg1 = x + ((size_t)(b0 + bb0 + 8) * TSEQ + tf) * IDIM;
    float4 xn0 = *(const float4*)xg0;
    float4 xn1 = *(const float4*)xg1;
    // stage chunk 0 into xbuf 0
    {
        f16x4 s0, s1;
        s0[0] = (_Float16)xn0.x; s0[1] = (_Float16)xn0.y;
        s0[2] = (_Float16)xn0.z; s0[3] = (_Float16)xn0.w;
        s1[0] = (_Float16)xn1.x; s1[1] = (_Float16)xn1.y;
        s1[2] = (_Float16)xn1.z; s1[3] = (_Float16)xn1.w;
        xstage[0][bb0][tf]     = s0;
        xstage[0][bb0 + 8][tf] = s1;
    }
    __syncthreads();                       // once; chunk-1 loads issued after
    xn0 = *(const float4*)(xg0 + TCH * IDIM);
    xn1 = *(const float4*)(xg1 + TCH * IDIM);

    // ---- anti-phase nudge (harmless; present in R9's best measurement) ----
    if (((blockIdx.x ^ (blockIdx.x >> 8)) & 1) != 0)
        __builtin_amdgcn_s_sleep(13);

    // ---- precomputed LDS byte offsets ----
    const int hbase = r * 128;
    const int hs0 = ((g16 + 0) << 4) ^ ((r & 7) << 4);
    const int hs1 = ((g16 + 4) << 4) ^ ((r & 7) << 4);
    int hw[4];
    #pragma unroll
    for (int q = 0; q < 4; ++q) {
        const int bat = 4 * g16 + q;
        hw[q] = (bat * 128 + (wv * 16 + r) * 2) ^ ((bat & 7) << 4);
    }
    char* hbB = (char*)&hbuf[0][0];
    const char* xsB = (const char*)&xstage[0][0][0];
    const int xrow = r * 33 * 8;           // row-r byte offset within one xbuf

    // x slice for step 0 (prefetched; subsequent slices loaded pre-barrier)
    f16x4 xv = *(const f16x4*)(xsB + xrow);

    // packed-f32 update for a cell pair (q0,q1): 13 pk-ops + 7x2 scalar trans
    auto cellpair = [&](const f32x4* acc, int q0, int q1, char* wb) {
        f32x2 ei, ef, eg, eo;
        ei[0] = EX2(-acc[0][q0]); ei[1] = EX2(-acc[0][q1]);
        ef[0] = EX2(-acc[1][q0]); ef[1] = EX2(-acc[1][q1]);
        eg[0] = EX2(-acc[2][q0]); eg[1] = EX2(-acc[2][q1]);
        eo[0] = EX2(-acc[3][q0]); eo[1] = EX2(-acc[3][q1]);
        const f32x2 one = {1.f, 1.f};
        f32x2 A  = one + ei, F = one + ef;
        f32x2 Gp = one + eg, Gm = one - eg;
        f32x2 P2 = A * Gp;
        f32x2 cr = { c_reg[q0], c_reg[q1] };
        f32x2 num = cr * P2 + Gm * F;          // v_pk_fma (contract)
        f32x2 den = P2 * F;
        f32x2 rd; rd[0] = RCP(den[0]); rd[1] = RCP(den[1]);
        f32x2 c = num * rd;
        c_reg[q0] = c[0]; c_reg[q1] = c[1];
        f32x2 uc = c * (2.0f * L2E);
        uc = __builtin_elementwise_max(uc, f32x2{-60.f, -60.f});  // lower clamp only
        f32x2 et; et[0] = EX2(-uc[0]); et[1] = EX2(-uc[1]);
        f32x2 hd = (one + eo) * (one + et);
        f32x2 rh; rh[0] = RCP(hd[0]); rh[1] = RCP(hd[1]);
        f32x2 h = (one - et) * rh;
        *(_Float16*)(wb + hw[q0]) = (_Float16)h[0];
        *(_Float16*)(wb + hw[q1]) = (_Float16)h[1];
    };

    // one sub-step; P = parity of t (compile-time)
    auto substep = [&](int t, int P) {
        const char* rb = hbB + P * 2048;         // h_{t-1}
        char*       wb = hbB + (P ^ 1) * 2048;   // h_t
        f16x8 a0 = *(const f16x8*)(rb + hbase + hs0);
        f16x8 a1 = *(const f16x8*)(rb + hbase + hs1);
        f16x8 ax;
        ax[0] = xv[0]; ax[1] = xv[1]; ax[2] = xv[2]; ax[3] = xv[3];
        ax[4] = (_Float16)1.0f; ax[5] = (_Float16)1.0f;   // bias slots (k=68,69)
        ax[6] = (_Float16)0.0f; ax[7] = (_Float16)0.0f;

        f32x4 acc[4];
        __builtin_amdgcn_s_setprio(1);
        #pragma unroll
        for (int t4 = 0; t4 < 4; ++t4) {
            f32x4 a;
            a = __builtin_amdgcn_mfma_f32_16x16x32_f16(a0, bfrag[t4][0], zero4, 0, 0, 0);
            a = __builtin_amdgcn_mfma_f32_16x16x32_f16(a1, bfrag[t4][1], a, 0, 0, 0);
            a = __builtin_amdgcn_mfma_f32_16x16x32_f16(ax, bfrag[t4][2], a, 0, 0, 0);
            acc[t4] = a;
        }
        __builtin_amdgcn_s_setprio(0);

        // prefetch NEXT step's x slice (no dependence on the step barrier;
        // LDS latency hides under the trans phase below)
        const int tn = t + 1;
        xv = *(const f16x4*)(xsB + ((tn >> 5) & 1) * 4224 + xrow + (tn & 31) * 8);

        cellpair(acc, 0, 1, wb);
        cellpair(acc, 2, 3, wb);
        STEP_BARRIER();
    };

    for (int t = 0; t < TSEQ; t += 2) {
        if ((t & (TCH - 1)) == 16) {
            const int c = t >> 5;                // current chunk
            if (c + 1 < NCH) {                   // stage chunk c+1 (regs arrived)
                f16x4 s0, s1;
                s0[0] = (_Float16)xn0.x; s0[1] = (_Float16)xn0.y;
                s0[2] = (_Float16)xn0.z; s0[3] = (_Float16)xn0.w;
                s1[0] = (_Float16)xn1.x; s1[1] = (_Float16)xn1.y;
                s1[2] = (_Float16)xn1.z; s1[3] = (_Float16)xn1.w;
                f16x4* dst = &xstage[(c + 1) & 1][0][0];
                dst[bb0 * 33 + tf]       = s0;
                dst[(bb0 + 8) * 33 + tf] = s1;
                if (c + 2 < NCH) {               // issue loads for chunk c+2
                    xn0 = *(const float4*)(xg0 + (size_t)(c + 2) * TCH * IDIM);
                    xn1 = *(const float4*)(xg1 + (size_t)(c + 2) * TCH * IDIM);
                }
            }
        }
        substep(t,     0);
        substep(t + 1, 1);
    }

    // ---- FC epilogue: final h in parity 0 (TRANS_511 wrote parity 0) ----
    #pragma unroll
    for (int q = 0; q < 4; ++q) {
        const int bat  = wv * 4 + q;
        const int byte = (bat * 128 + lane * 2) ^ ((bat & 7) << 4);
        float hv = (float)*(const _Float16*)(hbB + byte);
        float partial = hv * wfc;
        #pragma unroll
        for (int off = 32; off > 0; off >>= 1)
            partial += __shfl_down(partial, off);
        if (lane == 0) out[b0 + bat] = partial + bfc;
    }
}

extern "C" void kernel_launch(void* const* d_in, const int* in_sizes, int n_in,
                              void* d_out, int out_size, void* d_ws, size_t ws_size,
                              hipStream_t stream) {
    const float* x    = (const float*)d_in[0];
    const float* W_ih = (const float*)d_in[1];
    const float* W_hh = (const float*)d_in[2];
    const float* b_ih = (const float*)d_in[3];
    const float* b_hh = (const float*)d_in[4];
    const float* W_fc = (const float*)d_in[5];
    const float* b_fc = (const float*)d_in[6];
    float* out = (float*)d_out;

    const int B = in_sizes[0] / (TSEQ * IDIM);   // 8192
    lstm_fused<<<B / BPB, 256, 0, stream>>>(x, W_ih, W_hh, b_ih, b_hh, W_fc, b_fc, out);
}